// Round 18
// baseline (142.972 us; speedup 1.0000x reference)
//
#include <hip/hip_runtime.h>
#include <math.h>

#define HW_ 16384
#define SLOT_ 2097152ULL     // 128^3 floats (one attn plane)
#define BSTR_ 4194304ULL     // per-batch float stride in attn region (2 slots)

typedef __attribute__((ext_vector_type(8))) short short8v;   // 8 bf16 = 4 VGPR
typedef __attribute__((ext_vector_type(4))) float f32x4;

__device__ __forceinline__ unsigned short f2bf(float f) {
  unsigned int u = __float_as_uint(f);
  u = (u + 0x7FFFu + ((u >> 16) & 1u)) >> 16;   // RNE
  return (unsigned short)u;
}
__device__ __forceinline__ float bf2f(unsigned short h) {
  return __uint_as_float(((unsigned int)h) << 16);
}

// K1: fused q,k,v projection + e_w scores. Block = (b,h): one pixel row.
// R17 post-mortem: the 4-chunk stage/barrier/compute loop was barrier-bound
// (VALUBusy 37%, ~60% stall). New structure: stage the ENTIRE working set
// (x-slab 67.6KB + WvT 67.6KB + qkW 18.4KB = 153.6KB LDS, 1 block/CU), one
// barrier, then K=128 compute with ZERO barriers. Same fp32 math as R17.
__global__ void __launch_bounds__(512, 2)
qkv_proj(const float* __restrict__ x,
         const float* __restrict__ Wq, const float* __restrict__ bq,
         const float* __restrict__ Wk, const float* __restrict__ bk,
         const float* __restrict__ Wv, const float* __restrict__ bv,
         float* __restrict__ qT, float* __restrict__ kT,
         unsigned short* __restrict__ vA0,
         unsigned short* __restrict__ Ew, float* __restrict__ rsw) {
  __shared__ float LDS[38400];                       // 153.6 KB
  float (*XL)[132]  = (float(*)[132])LDS;            // [128 c][132] x slab
  float (*WL)[132]  = (float(*)[132])(LDS + 16896);  // [128 k][132] Wv^T [k][ch]
  float (*WTL)[36]  = (float(*)[36])(LDS + 33792);   // [128 c][36] qk W [c][och]
  int t = threadIdx.x;
  int blk = blockIdx.x;              // b*128 + h
  int b = blk >> 7, h = blk & 127;
  int p0 = h * 128;
  const float* xb = x + (size_t)b * 128 * HW_ + p0;
  // --- stage qk weights [c][och] (coalesced reads along c) ---
  for (int i = t; i < 4096; i += 512) {
    int o = i >> 7, c = i & 127;
    WTL[c][o] = (o < 16) ? Wq[o * 128 + c] : Wk[(o - 16) * 128 + c];
  }
  // --- stage x slab [c][px] (float4, fully coalesced, conflict-free writes) ---
#pragma unroll
  for (int it = 0; it < 8; ++it) {
    int gi = it * 512 + t;
    int c = gi >> 5;
    int p4 = (gi & 31) * 4;
    *(float4*)&XL[c][p4] = *(const float4*)&xb[(size_t)c * HW_ + p4];
  }
  // --- stage Wv transposed: WL[k][ch] (coalesced float4 reads along k) ---
#pragma unroll
  for (int it = 0; it < 8; ++it) {
    int gi = it * 512 + t;
    int ch = gi >> 5;
    int k4 = (gi & 31) * 4;
    float4 w = *(const float4*)&Wv[ch * 128 + k4];
    WL[k4 + 0][ch] = w.x;
    WL[k4 + 1][ch] = w.y;
    WL[k4 + 2][ch] = w.z;
    WL[k4 + 3][ch] = w.w;
  }
  int cg = t & 31;                   // v: 4-channel group; qk: och
  int pg = t >> 5;                   // 8-pixel group (0..15)
  float acc[4][8];
#pragma unroll
  for (int ci = 0; ci < 4; ++ci) {
    float bvv = bv[cg * 4 + ci];
#pragma unroll
    for (int pi = 0; pi < 8; ++pi) acc[ci][pi] = bvv;
  }
  float accqk[8];
  {
    float bias = (cg < 16) ? bq[cg] : bk[cg - 16];
#pragma unroll
    for (int pi = 0; pi < 8; ++pi) accqk[pi] = bias;
  }
  __syncthreads();   // single barrier: everything staged
  // --- barrier-free K=128 compute ---
#pragma unroll 4
  for (int kl = 0; kl < 128; ++kl) {
    float wa[4], xa[8];
    *(float4*)(wa)     = *(const float4*)&WL[kl][cg * 4];
    *(float4*)(xa)     = *(const float4*)&XL[kl][pg * 8];
    *(float4*)(xa + 4) = *(const float4*)&XL[kl][pg * 8 + 4];
    float wq = WTL[kl][cg];
#pragma unroll
    for (int ci = 0; ci < 4; ++ci)
#pragma unroll
      for (int pi = 0; pi < 8; ++pi)
        acc[ci][pi] = fmaf(wa[ci], xa[pi], acc[ci][pi]);
#pragma unroll
    for (int pi = 0; pi < 8; ++pi)
      accqk[pi] = fmaf(wq, xa[pi], accqk[pi]);
  }
  // v epilogue: bf16 [c][w] rows, 16B stores (global only)
#pragma unroll
  for (int ci = 0; ci < 4; ++ci) {
    union { unsigned short us[8]; uint4 v; } pk;
#pragma unroll
    for (int pi = 0; pi < 8; ++pi) pk.us[pi] = f2bf(acc[ci][pi]);
    *(uint4*)&vA0[(size_t)(b * 128 + h) * 16384 + (size_t)(cg * 4 + ci) * 128 + pg * 8] = pk.v;
  }
  __syncthreads();   // XL now dead everywhere -> safe to overlay with QKs
  // qk: stage pixel-major QKs[px][och] (overlays XL region)
  float (*QKs)[36] = (float(*)[36])LDS;
#pragma unroll
  for (int pi = 0; pi < 8; ++pi)
    QKs[pg * 8 + pi][cg] = accqk[pi];
  __syncthreads();
  if (t >= 256) {
    // waves 4-7: qT/kT global writes
    int tt = t - 256;
    int px_ = tt >> 1, sel = tt & 1;    // px_ = w
    const float* qr = &QKs[px_][sel * 16];
    float4 r0 = *(const float4*)(qr);
    float4 r1 = *(const float4*)(qr + 4);
    float4 r2 = *(const float4*)(qr + 8);
    float4 r3 = *(const float4*)(qr + 12);
    float* dstT = (sel ? kT : qT) + ((size_t)(b * HW_ + px_ * 128 + h)) * 16;
    *(float4*)(dstT)      = r0;
    *(float4*)(dstT + 4)  = r1;
    *(float4*)(dstT + 8)  = r2;
    *(float4*)(dstT + 12) = r3;
  } else {
    // waves 0-3: stage Qs/Ks [c][px] (overlay dead WL region)
    float (*Qs)[132] = (float(*)[132])(LDS + 16896);
    float (*Ks)[132] = (float(*)[132])(LDS + 16896 + 2112);
    int cc = t & 15, pb = (t >> 4) * 8;
#pragma unroll
    for (int u = 0; u < 8; ++u) {
      Qs[cc][pb + u] = QKs[pb + u][cc];
      Ks[cc][pb + u] = QKs[pb + u][16 + cc];
    }
  }
  __syncthreads();
  if (t < 256) {
    float (*Qs)[132] = (float(*)[132])(LDS + 16896);
    float (*Ks)[132] = (float(*)[132])(LDS + 16896 + 2112);
    int tr = (t >> 4) * 8;
    int ty = (t & 15) * 8;
    float sc_[8][8] = {{0.f}};
#pragma unroll
    for (int c = 0; c < 16; ++c) {
      float qa[8], ka[8];
      *(float4*)(qa)     = *(const float4*)&Qs[c][tr];
      *(float4*)(qa + 4) = *(const float4*)&Qs[c][tr + 4];
      *(float4*)(ka)     = *(const float4*)&Ks[c][ty];
      *(float4*)(ka + 4) = *(const float4*)&Ks[c][ty + 4];
#pragma unroll
      for (int u = 0; u < 8; ++u)
#pragma unroll
        for (int v = 0; v < 8; ++v)
          sc_[u][v] = fmaf(qa[u], ka[v], sc_[u][v]);
    }
    float rp[8];
#pragma unroll
    for (int u = 0; u < 8; ++u) {
      rp[u] = 0.f;
#pragma unroll
      for (int v = 0; v < 8; ++v) {
        float e = __expf(sc_[u][v]);
        sc_[u][v] = e;
        rp[u] += e;
      }
    }
    unsigned short* out = Ew + (size_t)blk * 16384;
#pragma unroll
    for (int u = 0; u < 8; ++u) {
      union { unsigned short us[8]; uint4 v; } pk;
#pragma unroll
      for (int v = 0; v < 8; ++v) pk.us[v] = f2bf(sc_[u][v]);
      *(uint4*)&out[(tr + u) * 128 + ty] = pk.v;
    }
#pragma unroll
    for (int u = 0; u < 8; ++u) {
      rp[u] += __shfl_xor(rp[u], 1);
      rp[u] += __shfl_xor(rp[u], 2);
      rp[u] += __shfl_xor(rp[u], 4);
      rp[u] += __shfl_xor(rp[u], 8);
    }
    if ((t & 15) == 0) {
#pragma unroll
      for (int u = 0; u < 8; ++u) rsw[(size_t)blk * 128 + tr + u] = rp[u];
    }
  }
}

// K2: e_h score GEMM + exp + row-sums (reads contiguous qT/kT; diag MASK).
__global__ void score_h(const float* __restrict__ Q, const float* __restrict__ K,
                        unsigned short* __restrict__ E, float* __restrict__ rsum,
                        size_t ebs, size_t eoff) {
  __shared__ float Qs[16][132];
  __shared__ float Ks[16][132];
  int slab = blockIdx.x;            // b*128 + s
  int b = slab >> 7, s = slab & 127;
  const float* qb = Q + (size_t)slab * 2048;
  const float* kb = K + (size_t)slab * 2048;
  int t = threadIdx.x;
  int cc = t & 15;
  int pb = (t >> 4) * 8;
#pragma unroll
  for (int u = 0; u < 8; ++u) {
    Qs[cc][pb + u] = qb[(size_t)(pb + u) * 16 + cc];
    Ks[cc][pb + u] = kb[(size_t)(pb + u) * 16 + cc];
  }
  __syncthreads();
  int tr = (t >> 4) * 8;
  int ty = (t & 15) * 8;
  float acc[8][8] = {{0.f}};
#pragma unroll
  for (int c = 0; c < 16; ++c) {
    float qa[8], ka[8];
    *(float4*)(qa)     = *(const float4*)&Qs[c][tr];
    *(float4*)(qa + 4) = *(const float4*)&Qs[c][tr + 4];
    *(float4*)(ka)     = *(const float4*)&Ks[c][ty];
    *(float4*)(ka + 4) = *(const float4*)&Ks[c][ty + 4];
#pragma unroll
    for (int u = 0; u < 8; ++u)
#pragma unroll
      for (int v = 0; v < 8; ++v)
        acc[u][v] = fmaf(qa[u], ka[v], acc[u][v]);
  }
  float rp[8];
#pragma unroll
  for (int u = 0; u < 8; ++u) {
    rp[u] = 0.f;
#pragma unroll
    for (int v = 0; v < 8; ++v) {
      float e = __expf(acc[u][v]);
      if ((tr + u) == (ty + v)) e = 0.f;
      acc[u][v] = e;
      rp[u] += e;
    }
  }
  unsigned short* out = E + (size_t)b * ebs + eoff + (size_t)s * 16384;
#pragma unroll
  for (int u = 0; u < 8; ++u) {
    union { unsigned short us[8]; uint4 v; } pk;
#pragma unroll
    for (int v = 0; v < 8; ++v) pk.us[v] = f2bf(acc[u][v]);
    *(uint4*)&out[(tr + u) * 128 + ty] = pk.v;
  }
#pragma unroll
  for (int u = 0; u < 8; ++u) {
    rp[u] += __shfl_xor(rp[u], 1);
    rp[u] += __shfl_xor(rp[u], 2);
    rp[u] += __shfl_xor(rp[u], 4);
    rp[u] += __shfl_xor(rp[u], 8);
  }
  if ((t & 15) == 0) {
#pragma unroll
    for (int u = 0; u < 8; ++u) rsum[(size_t)slab * 128 + tr + u] = rp[u];
  }
}

// K3: vA1[b][w][c][h] = vA0[b][h][c][w]; blocks 0..255 also compute invd.
__global__ void trans_v(const unsigned short* __restrict__ vA0, unsigned short* __restrict__ vA1,
                        const float* __restrict__ rsw, const float* __restrict__ rsh,
                        float* __restrict__ dij, float* __restrict__ dji) {
  __shared__ unsigned short tile[64][65];
  int blk = blockIdx.x;            // b(4)*c(128)*quad(4)
  int q = blk & 3, c = (blk >> 2) & 127, b = blk >> 9;
  int h0 = (q >> 1) * 64, w0 = (q & 1) * 64;
  int t = threadIdx.x, lane = t & 63, r0 = (t >> 6) * 16;
  for (int r = r0; r < r0 + 16; ++r)
    tile[r][lane] = vA0[(size_t)(b * 128 + h0 + r) * 16384 + c * 128 + w0 + lane];
  __syncthreads();
  for (int r = r0; r < r0 + 16; ++r)
    vA1[(size_t)(b * 128 + w0 + r) * 16384 + c * 128 + h0 + lane] = tile[lane][r];
  if (blk < 256) {
    int p = blk * 256 + t;
    int bb = p >> 14, rem = p & 16383, i = rem >> 7, j = rem & 127;
    float d = rsw[p] + rsh[(size_t)bb * HW_ + j * 128 + i];
    float r = 1.0f / d;
    dij[p] = r;
    dji[(size_t)bb * HW_ + j * 128 + i] = r;
  }
}

// K4: fused PV MFMA. blk<512: (A=vA0,B=E_w) -> ow bf16 [b][c][h][w].
//     blk>=512: (A=vA1,B=E_h odd slots) -> oh bf16 (even attn slots).
__global__ void pv2(const unsigned short* __restrict__ vA0,
                    const unsigned short* __restrict__ vA1,
                    const unsigned short* __restrict__ Ew,
                    const unsigned short* __restrict__ EhB,
                    const float* __restrict__ dij, const float* __restrict__ dji,
                    unsigned short* __restrict__ ow, unsigned short* __restrict__ ohb) {
  __shared__ unsigned short Al[128][44];
  __shared__ unsigned short Bl[128][44];
  int blk = blockIdx.x;
  int m = blk >> 9;
  int slab = blk & 511;
  int s = slab & 127, b = slab >> 7;
  int t = threadIdx.x;
  int wv = t >> 6, l = t & 63;
  int wc = (wv >> 1) * 64, wx = (wv & 1) * 64;
  const unsigned short* vs = (m ? vA1 : vA0) + (size_t)slab * 16384;
  const unsigned short* es = m ? (EhB + (size_t)b * 8388608 + 4194304 + (size_t)s * 16384)
                               : (Ew + (size_t)slab * 16384);
  const float* invd = m ? dji : dij;
  f32x4 acc[4][4];
#pragma unroll
  for (int mi = 0; mi < 4; ++mi)
#pragma unroll
    for (int ni = 0; ni < 4; ++ni) acc[mi][ni] = (f32x4){0.f, 0.f, 0.f, 0.f};
  int lrow = t >> 2, lq = t & 3;
  int lm = l & 15, lk = (l >> 4) * 4;
  for (int y0 = 0; y0 < 128; y0 += 32) {
#pragma unroll
    for (int r = 0; r < 2; ++r) {
      int rr = lrow + r * 64;
      uint4 av = *(const uint4*)(vs + (size_t)rr * 128 + y0 + lq * 8);
      uint4 bv = *(const uint4*)(es + (size_t)rr * 128 + y0 + lq * 8);
      *(uint2*)&Al[rr][lq * 8]     = make_uint2(av.x, av.y);
      *(uint2*)&Al[rr][lq * 8 + 4] = make_uint2(av.z, av.w);
      *(uint2*)&Bl[rr][lq * 8]     = make_uint2(bv.x, bv.y);
      *(uint2*)&Bl[rr][lq * 8 + 4] = make_uint2(bv.z, bv.w);
    }
    __syncthreads();
    short8v af[4], bf[4];
#pragma unroll
    for (int mi = 0; mi < 4; ++mi) {
      const unsigned short* ap = &Al[wc + mi * 16 + lm][lk];
      union { uint2 p[2]; short8v v; } u;
      u.p[0] = *(const uint2*)ap;
      u.p[1] = *(const uint2*)(ap + 16);
      af[mi] = u.v;
    }
#pragma unroll
    for (int ni = 0; ni < 4; ++ni) {
      const unsigned short* bp = &Bl[wx + ni * 16 + lm][lk];
      union { uint2 p[2]; short8v v; } u;
      u.p[0] = *(const uint2*)bp;
      u.p[1] = *(const uint2*)(bp + 16);
      bf[ni] = u.v;
    }
#pragma unroll
    for (int mi = 0; mi < 4; ++mi)
#pragma unroll
      for (int ni = 0; ni < 4; ++ni)
        acc[mi][ni] = __builtin_amdgcn_mfma_f32_16x16x32_bf16(af[mi], bf[ni], acc[mi][ni], 0, 0, 0);
    __syncthreads();
  }
  int lr4 = (l >> 4) * 4;
  unsigned short* dst = m ? ohb : ow;
#pragma unroll
  for (int ni = 0; ni < 4; ++ni) {
    int xx = wx + ni * 16 + lm;
    float idv = invd[(size_t)(b * 128 + s) * 128 + xx];
#pragma unroll
    for (int mi = 0; mi < 4; ++mi) {
#pragma unroll
      for (int r = 0; r < 4; ++r) {
        int c = wc + mi * 16 + lr4 + r;
        size_t idx = m ? ((size_t)b * 8388608 + (size_t)s * 16384 + (size_t)c * 128 + xx)
                       : ((((size_t)(b * 128 + c)) * 128 + s) * 128 + xx);
        dst[idx] = f2bf(acc[mi][ni][r] * idv);
      }
    }
  }
}

// K5: final out = g*(ow + oh^T) + x.
__global__ void merge2(const unsigned short* __restrict__ ow,
                       const unsigned short* __restrict__ ohp,
                       const float* __restrict__ xin, const float* __restrict__ gamma,
                       float* __restrict__ outp) {
  __shared__ float tile[64][65];
  int blk = blockIdx.x;
  int q = blk & 3, c = (blk >> 2) & 127, b = blk >> 9;
  int h0 = (q >> 1) * 64, w0 = (q & 1) * 64;
  int t = threadIdx.x, lane = t & 63, r0 = (t >> 6) * 16;
  for (int r = r0; r < r0 + 16; ++r)
    tile[r][lane] =
        bf2f(ohp[(size_t)b * 8388608ULL + (size_t)(w0 + r) * 16384 + c * 128 + h0 + lane]);
  __syncthreads();
  float g = gamma[0];
  for (int r = r0; r < r0 + 16; ++r) {
    size_t a = (((size_t)(b * 128 + c)) * 128 + h0 + r) * 128 + w0 + lane;
    outp[a] = g * (bf2f(ow[a]) + tile[lane][r]) + xin[a];
  }
}

// K6: attn writer.
template <int HM>
__global__ void ret_write(const unsigned short* __restrict__ src, const float* __restrict__ invd,
                          float* __restrict__ retb, size_t sbs, size_t soff) {
  __shared__ float tile[128][129];
  __shared__ float idv[128];
  int slab = blockIdx.x;            // b*128 + i
  int b = slab >> 7, i = slab & 127;
  int t = threadIdx.x;
  const unsigned short* sp = src + (size_t)b * sbs + soff;
#pragma unroll
  for (int r = 0; r < 8; ++r) {
    int idx = r * 2048 + t * 8;
    int j = idx >> 7, y = idx & 127;
    uint4 raw;
    if (HM == 0)
      raw = *(const uint4*)(sp + (size_t)i * 16384 + j * 128 + y);
    else
      raw = *(const uint4*)(sp + (size_t)j * 16384 + i * 128 + y);
    unsigned int wd[4] = {raw.x, raw.y, raw.z, raw.w};
#pragma unroll
    for (int e = 0; e < 4; ++e) {
      tile[j][y + 2 * e]     = __uint_as_float((wd[e] & 0xFFFFu) << 16);
      tile[j][y + 2 * e + 1] = __uint_as_float(wd[e] & 0xFFFF0000u);
    }
  }
  if (t < 128) idv[t] = invd[(size_t)slab * 128 + t];
  __syncthreads();
  float* dp = retb + (size_t)b * BSTR_ + (HM == 0 ? SLOT_ : 0);
#pragma unroll
  for (int r = 0; r < 16; ++r) {
    int idx = r * 1024 + t * 4;
    int y = idx >> 7, j = idx & 127;
    float4 o;
    o.x = tile[j][y]     * idv[j];
    o.y = tile[j + 1][y] * idv[j + 1];
    o.z = tile[j + 2][y] * idv[j + 2];
    o.w = tile[j + 3][y] * idv[j + 3];
    *(float4*)&dp[(size_t)y * 16384 + i * 128 + j] = o;
  }
}

extern "C" void kernel_launch(void* const* d_in, const int* in_sizes, int n_in,
                              void* d_out, int out_size, void* d_ws, size_t ws_size,
                              hipStream_t stream) {
  const float* x     = (const float*)d_in[0];
  const float* Wq    = (const float*)d_in[1];
  const float* bq    = (const float*)d_in[2];
  const float* Wk    = (const float*)d_in[3];
  const float* bk    = (const float*)d_in[4];
  const float* Wv    = (const float*)d_in[5];
  const float* bv    = (const float*)d_in[6];
  const float* gamma = (const float*)d_in[7];

  float* outp = (float*)d_out;                 // final out (8M floats)
  float* retb = outp + (size_t)8388608;        // attn region [b][2][y][i][j]
  unsigned short* ohb = (unsigned short*)retb; // bf16 oh in even slots (pre-ret_write)
  unsigned short* ehb = (unsigned short*)retb; // bf16 E_h in odd slots

  float* ws      = (float*)d_ws;
  float* qT      = ws + (size_t)2097152;
  float* kT      = ws + (size_t)3145728;
  unsigned short* ow  = (unsigned short*)ws;
  unsigned short* vA0 = (unsigned short*)(ws + (size_t)4194304);
  unsigned short* vA1 = (unsigned short*)(ws + (size_t)8388608);
  unsigned short* E_w = (unsigned short*)(ws + (size_t)12582912);
  float* rsum_w  = ws + (size_t)16777216;
  float* rsum_h  = ws + (size_t)16842752;
  float* invd_ij = ws + (size_t)16908288;
  float* invd_ji = ws + (size_t)16973824;

  qkv_proj<<<512, 512, 0, stream>>>(x, Wq, bq, Wk, bk, Wv, bv,
                                    qT, kT, vA0, E_w, rsum_w);
  score_h<<<512, 256, 0, stream>>>(qT, kT, ehb, rsum_h,
                                   (size_t)8388608, (size_t)4194304);
  trans_v<<<2048, 256, 0, stream>>>(vA0, vA1, rsum_w, rsum_h, invd_ij, invd_ji);
  pv2<<<1024, 256, 0, stream>>>(vA0, vA1, E_w, ehb, invd_ij, invd_ji, ow, ohb);
  merge2<<<2048, 256, 0, stream>>>(ow, ohb, x, gamma, outp);
  ret_write<1><<<512, 256, 0, stream>>>(ehb, invd_ij, retb, (size_t)8388608, (size_t)4194304);
  ret_write<0><<<512, 256, 0, stream>>>(E_w, invd_ij, retb, (size_t)2097152, (size_t)0);
}

// Round 19
// 111.693 us; speedup vs baseline: 1.2800x; 1.2800x over previous
//
#include <hip/hip_runtime.h>
#include <math.h>

#define HW_ 16384
#define SLOT_ 2097152ULL     // 128^3 floats (one attn plane)
#define BSTR_ 4194304ULL     // per-batch float stride in attn region (2 slots)

typedef __attribute__((ext_vector_type(8))) short short8v;   // 8 bf16 = 4 VGPR
typedef __attribute__((ext_vector_type(4))) float f32x4;

__device__ __forceinline__ unsigned short f2bf(float f) {
  unsigned int u = __float_as_uint(f);
  u = (u + 0x7FFFu + ((u >> 16) & 1u)) >> 16;   // RNE
  return (unsigned short)u;
}
__device__ __forceinline__ float bf2f(unsigned short h) {
  return __uint_as_float(((unsigned int)h) << 16);
}

// K1: fused q,k,v projection (MFMA) + e_w scores. Block = (b,h), 256 threads.
// R18 post-mortem: fp32 VALU was the floor (~5248 FMA/thread). Projections are
// K=128 matmuls -> bf16 MFMA (pv2's verified fragment layout). LDS: bf16
// WqkL[32][136] + WvL[128][136] + XT[128][136] (x slab with k row-contiguous)
// = 78KB -> 2 blocks/CU. B-fragments (XT) shared by v- and qk-GEMMs.
__global__ void __launch_bounds__(256, 2)
qkv_proj(const float* __restrict__ x,
         const float* __restrict__ Wq, const float* __restrict__ bq,
         const float* __restrict__ Wk, const float* __restrict__ bk,
         const float* __restrict__ Wv, const float* __restrict__ bv,
         float* __restrict__ qT, float* __restrict__ kT,
         unsigned short* __restrict__ vA0,
         unsigned short* __restrict__ Ew, float* __restrict__ rsw) {
  __shared__ unsigned short LDSU[39168];   // 78.3 KB
  unsigned short (*WqkL)[136] = (unsigned short(*)[136])LDSU;            // [32][136]
  unsigned short (*WvL)[136]  = (unsigned short(*)[136])(LDSU + 4352);   // [128][136]
  unsigned short (*XT)[136]   = (unsigned short(*)[136])(LDSU + 21760);  // [128 px][136 k]
  int t = threadIdx.x;
  int blk = blockIdx.x;              // b*128 + h
  int b = blk >> 7, h = blk & 127;
  // --- stage Wqk bf16 [och][k] (och<16: q, >=16: k) ---
  {
    int och = t >> 3, kb = (t & 7) * 16;
    const float* src = (och < 16 ? Wq + och * 128 : Wk + (och - 16) * 128) + kb;
    union { unsigned short us[8]; uint4 v; } p0, p1;
#pragma unroll
    for (int j = 0; j < 8; ++j) p0.us[j] = f2bf(src[j]);
#pragma unroll
    for (int j = 0; j < 8; ++j) p1.us[j] = f2bf(src[8 + j]);
    *(uint4*)&WqkL[och][kb]     = p0.v;
    *(uint4*)&WqkL[och][kb + 8] = p1.v;
  }
  // --- stage Wv bf16 [c][k] (coalesced fp32 reads) ---
  {
    int c = t >> 1, kb = (t & 1) * 64;
    const float* src = Wv + c * 128 + kb;
#pragma unroll
    for (int g = 0; g < 8; ++g) {
      union { unsigned short us[8]; uint4 v; } p;
#pragma unroll
      for (int j = 0; j < 8; ++j) p.us[j] = f2bf(src[g * 8 + j]);
      *(uint4*)&WvL[c][kb + g * 8] = p.v;
    }
  }
  // --- stage XT bf16 [px][k]: coalesced x reads, column LDS writes ---
  {
    int k = t >> 1, pxb = (t & 1) * 64;
    const float* src = x + (size_t)b * 128 * HW_ + (size_t)k * HW_ + h * 128 + pxb;
#pragma unroll
    for (int j = 0; j < 64; ++j)
      XT[pxb + j][k] = f2bf(src[j]);
  }
  int wv = t >> 6, l = t & 63;
  int lm = l & 15, lk = (l >> 4) * 4, lr4 = (l >> 4) * 4;
  int wc = (wv >> 1) * 64, wx = (wv & 1) * 64;
  int ocht = (wv >> 1) * 16;
  // bias registers
  float bvr[4][4];
#pragma unroll
  for (int mi = 0; mi < 4; ++mi)
#pragma unroll
    for (int r = 0; r < 4; ++r) bvr[mi][r] = bv[wc + mi * 16 + lr4 + r];
  float bqk[4];
#pragma unroll
  for (int r = 0; r < 4; ++r) {
    int och = ocht + lr4 + r;
    bqk[r] = (och < 16) ? bq[och] : bk[och - 16];
  }
  f32x4 acc[4][4];
#pragma unroll
  for (int mi = 0; mi < 4; ++mi)
#pragma unroll
    for (int ni = 0; ni < 4; ++ni) acc[mi][ni] = (f32x4){0.f, 0.f, 0.f, 0.f};
  f32x4 acc2[4];
#pragma unroll
  for (int ni = 0; ni < 4; ++ni) acc2[ni] = (f32x4){0.f, 0.f, 0.f, 0.f};
  __syncthreads();
  // --- MFMA K-loop (B fragments shared by v and qk) ---
  for (int y0 = 0; y0 < 128; y0 += 32) {
    short8v bf[4];
#pragma unroll
    for (int ni = 0; ni < 4; ++ni) {
      const unsigned short* bp = &XT[wx + ni * 16 + lm][y0 + lk];
      union { uint2 p[2]; short8v v; } u;
      u.p[0] = *(const uint2*)bp;
      u.p[1] = *(const uint2*)(bp + 16);
      bf[ni] = u.v;
    }
#pragma unroll
    for (int mi = 0; mi < 4; ++mi) {
      const unsigned short* ap = &WvL[wc + mi * 16 + lm][y0 + lk];
      union { uint2 p[2]; short8v v; } u;
      u.p[0] = *(const uint2*)ap;
      u.p[1] = *(const uint2*)(ap + 16);
      short8v af = u.v;
#pragma unroll
      for (int ni = 0; ni < 4; ++ni)
        acc[mi][ni] = __builtin_amdgcn_mfma_f32_16x16x32_bf16(af, bf[ni], acc[mi][ni], 0, 0, 0);
    }
    {
      const unsigned short* ap = &WqkL[ocht + lm][y0 + lk];
      union { uint2 p[2]; short8v v; } u;
      u.p[0] = *(const uint2*)ap;
      u.p[1] = *(const uint2*)(ap + 16);
      short8v aq = u.v;
#pragma unroll
      for (int ni = 0; ni < 4; ++ni)
        acc2[ni] = __builtin_amdgcn_mfma_f32_16x16x32_bf16(aq, bf[ni], acc2[ni], 0, 0, 0);
    }
  }
  // --- v epilogue: vA0[b][h][c][px] bf16 ---
#pragma unroll
  for (int ni = 0; ni < 4; ++ni) {
    int px = wx + ni * 16 + lm;
#pragma unroll
    for (int mi = 0; mi < 4; ++mi)
#pragma unroll
      for (int r = 0; r < 4; ++r) {
        int c = wc + mi * 16 + lr4 + r;
        vA0[(size_t)(b * 128 + h) * 16384 + (size_t)c * 128 + px] =
            f2bf(acc[mi][ni][r] + bvr[mi][r]);
      }
  }
  __syncthreads();   // XT dead -> overlay QKs
  // --- qk epilogue: QKs[px][och] fp32 (overlay XT region) ---
  float (*QKs)[36] = (float(*)[36])(LDSU + 21760);
#pragma unroll
  for (int ni = 0; ni < 4; ++ni) {
    int px = (wv & 1) * 64 + ni * 16 + lm;
#pragma unroll
    for (int r = 0; r < 4; ++r)
      QKs[px][ocht + lr4 + r] = acc2[ni][r] + bqk[r];
  }
  __syncthreads();
  // qT/kT global writes (for score_h)
  {
    int px_ = t >> 1, sel = t & 1;    // px_ = w
    const float* qr = &QKs[px_][sel * 16];
    float4 r0 = *(const float4*)(qr);
    float4 r1 = *(const float4*)(qr + 4);
    float4 r2 = *(const float4*)(qr + 8);
    float4 r3 = *(const float4*)(qr + 12);
    float* dstT = (sel ? kT : qT) + ((size_t)(b * HW_ + px_ * 128 + h)) * 16;
    *(float4*)(dstT)      = r0;
    *(float4*)(dstT + 4)  = r1;
    *(float4*)(dstT + 8)  = r2;
    *(float4*)(dstT + 12) = r3;
  }
  // stage Qs/Ks [c][px] (overlay WvL region)
  float (*Qs)[132] = (float(*)[132])(LDSU + 4352);
  float (*Ks)[132] = (float(*)[132])(LDSU + 8576);
  {
    int cc = t & 15, pb = (t >> 4) * 8;
#pragma unroll
    for (int u = 0; u < 8; ++u) {
      Qs[cc][pb + u] = QKs[pb + u][cc];
      Ks[cc][pb + u] = QKs[pb + u][16 + cc];
    }
  }
  __syncthreads();
  // fused e_w score (fp32, unchanged numerics path)
  {
    int tr = (t >> 4) * 8;
    int ty = (t & 15) * 8;
    float sc_[8][8] = {{0.f}};
#pragma unroll
    for (int c = 0; c < 16; ++c) {
      float qa[8], ka[8];
      *(float4*)(qa)     = *(const float4*)&Qs[c][tr];
      *(float4*)(qa + 4) = *(const float4*)&Qs[c][tr + 4];
      *(float4*)(ka)     = *(const float4*)&Ks[c][ty];
      *(float4*)(ka + 4) = *(const float4*)&Ks[c][ty + 4];
#pragma unroll
      for (int u = 0; u < 8; ++u)
#pragma unroll
        for (int v = 0; v < 8; ++v)
          sc_[u][v] = fmaf(qa[u], ka[v], sc_[u][v]);
    }
    float rp[8];
#pragma unroll
    for (int u = 0; u < 8; ++u) {
      rp[u] = 0.f;
#pragma unroll
      for (int v = 0; v < 8; ++v) {
        float e = __expf(sc_[u][v]);
        sc_[u][v] = e;
        rp[u] += e;
      }
    }
    unsigned short* out = Ew + (size_t)blk * 16384;
#pragma unroll
    for (int u = 0; u < 8; ++u) {
      union { unsigned short us[8]; uint4 v; } pk;
#pragma unroll
      for (int v = 0; v < 8; ++v) pk.us[v] = f2bf(sc_[u][v]);
      *(uint4*)&out[(tr + u) * 128 + ty] = pk.v;
    }
#pragma unroll
    for (int u = 0; u < 8; ++u) {
      rp[u] += __shfl_xor(rp[u], 1);
      rp[u] += __shfl_xor(rp[u], 2);
      rp[u] += __shfl_xor(rp[u], 4);
      rp[u] += __shfl_xor(rp[u], 8);
    }
    if ((t & 15) == 0) {
#pragma unroll
      for (int u = 0; u < 8; ++u) rsw[(size_t)blk * 128 + tr + u] = rp[u];
    }
  }
}

// K2: e_h score GEMM + exp + row-sums (reads contiguous qT/kT; diag MASK).
__global__ void score_h(const float* __restrict__ Q, const float* __restrict__ K,
                        unsigned short* __restrict__ E, float* __restrict__ rsum,
                        size_t ebs, size_t eoff) {
  __shared__ float Qs[16][132];
  __shared__ float Ks[16][132];
  int slab = blockIdx.x;            // b*128 + s
  int b = slab >> 7, s = slab & 127;
  const float* qb = Q + (size_t)slab * 2048;
  const float* kb = K + (size_t)slab * 2048;
  int t = threadIdx.x;
  int cc = t & 15;
  int pb = (t >> 4) * 8;
#pragma unroll
  for (int u = 0; u < 8; ++u) {
    Qs[cc][pb + u] = qb[(size_t)(pb + u) * 16 + cc];
    Ks[cc][pb + u] = kb[(size_t)(pb + u) * 16 + cc];
  }
  __syncthreads();
  int tr = (t >> 4) * 8;
  int ty = (t & 15) * 8;
  float acc[8][8] = {{0.f}};
#pragma unroll
  for (int c = 0; c < 16; ++c) {
    float qa[8], ka[8];
    *(float4*)(qa)     = *(const float4*)&Qs[c][tr];
    *(float4*)(qa + 4) = *(const float4*)&Qs[c][tr + 4];
    *(float4*)(ka)     = *(const float4*)&Ks[c][ty];
    *(float4*)(ka + 4) = *(const float4*)&Ks[c][ty + 4];
#pragma unroll
    for (int u = 0; u < 8; ++u)
#pragma unroll
      for (int v = 0; v < 8; ++v)
        acc[u][v] = fmaf(qa[u], ka[v], acc[u][v]);
  }
  float rp[8];
#pragma unroll
  for (int u = 0; u < 8; ++u) {
    rp[u] = 0.f;
#pragma unroll
    for (int v = 0; v < 8; ++v) {
      float e = __expf(acc[u][v]);
      if ((tr + u) == (ty + v)) e = 0.f;
      acc[u][v] = e;
      rp[u] += e;
    }
  }
  unsigned short* out = E + (size_t)b * ebs + eoff + (size_t)s * 16384;
#pragma unroll
  for (int u = 0; u < 8; ++u) {
    union { unsigned short us[8]; uint4 v; } pk;
#pragma unroll
    for (int v = 0; v < 8; ++v) pk.us[v] = f2bf(acc[u][v]);
    *(uint4*)&out[(tr + u) * 128 + ty] = pk.v;
  }
#pragma unroll
  for (int u = 0; u < 8; ++u) {
    rp[u] += __shfl_xor(rp[u], 1);
    rp[u] += __shfl_xor(rp[u], 2);
    rp[u] += __shfl_xor(rp[u], 4);
    rp[u] += __shfl_xor(rp[u], 8);
  }
  if ((t & 15) == 0) {
#pragma unroll
    for (int u = 0; u < 8; ++u) rsum[(size_t)slab * 128 + tr + u] = rp[u];
  }
}

// K3: vA1[b][w][c][h] = vA0[b][h][c][w]; blocks 0..255 also compute invd.
__global__ void trans_v(const unsigned short* __restrict__ vA0, unsigned short* __restrict__ vA1,
                        const float* __restrict__ rsw, const float* __restrict__ rsh,
                        float* __restrict__ dij, float* __restrict__ dji) {
  __shared__ unsigned short tile[64][65];
  int blk = blockIdx.x;            // b(4)*c(128)*quad(4)
  int q = blk & 3, c = (blk >> 2) & 127, b = blk >> 9;
  int h0 = (q >> 1) * 64, w0 = (q & 1) * 64;
  int t = threadIdx.x, lane = t & 63, r0 = (t >> 6) * 16;
  for (int r = r0; r < r0 + 16; ++r)
    tile[r][lane] = vA0[(size_t)(b * 128 + h0 + r) * 16384 + c * 128 + w0 + lane];
  __syncthreads();
  for (int r = r0; r < r0 + 16; ++r)
    vA1[(size_t)(b * 128 + w0 + r) * 16384 + c * 128 + h0 + lane] = tile[lane][r];
  if (blk < 256) {
    int p = blk * 256 + t;
    int bb = p >> 14, rem = p & 16383, i = rem >> 7, j = rem & 127;
    float d = rsw[p] + rsh[(size_t)bb * HW_ + j * 128 + i];
    float r = 1.0f / d;
    dij[p] = r;
    dji[(size_t)bb * HW_ + j * 128 + i] = r;
  }
}

// K4: fused PV MFMA. blk<512: (A=vA0,B=E_w) -> ow bf16 [b][c][h][w].
//     blk>=512: (A=vA1,B=E_h odd slots) -> oh bf16 (even attn slots).
__global__ void pv2(const unsigned short* __restrict__ vA0,
                    const unsigned short* __restrict__ vA1,
                    const unsigned short* __restrict__ Ew,
                    const unsigned short* __restrict__ EhB,
                    const float* __restrict__ dij, const float* __restrict__ dji,
                    unsigned short* __restrict__ ow, unsigned short* __restrict__ ohb) {
  __shared__ unsigned short Al[128][44];
  __shared__ unsigned short Bl[128][44];
  int blk = blockIdx.x;
  int m = blk >> 9;
  int slab = blk & 511;
  int s = slab & 127, b = slab >> 7;
  int t = threadIdx.x;
  int wv = t >> 6, l = t & 63;
  int wc = (wv >> 1) * 64, wx = (wv & 1) * 64;
  const unsigned short* vs = (m ? vA1 : vA0) + (size_t)slab * 16384;
  const unsigned short* es = m ? (EhB + (size_t)b * 8388608 + 4194304 + (size_t)s * 16384)
                               : (Ew + (size_t)slab * 16384);
  const float* invd = m ? dji : dij;
  f32x4 acc[4][4];
#pragma unroll
  for (int mi = 0; mi < 4; ++mi)
#pragma unroll
    for (int ni = 0; ni < 4; ++ni) acc[mi][ni] = (f32x4){0.f, 0.f, 0.f, 0.f};
  int lrow = t >> 2, lq = t & 3;
  int lm = l & 15, lk = (l >> 4) * 4;
  for (int y0 = 0; y0 < 128; y0 += 32) {
#pragma unroll
    for (int r = 0; r < 2; ++r) {
      int rr = lrow + r * 64;
      uint4 av = *(const uint4*)(vs + (size_t)rr * 128 + y0 + lq * 8);
      uint4 bv = *(const uint4*)(es + (size_t)rr * 128 + y0 + lq * 8);
      *(uint2*)&Al[rr][lq * 8]     = make_uint2(av.x, av.y);
      *(uint2*)&Al[rr][lq * 8 + 4] = make_uint2(av.z, av.w);
      *(uint2*)&Bl[rr][lq * 8]     = make_uint2(bv.x, bv.y);
      *(uint2*)&Bl[rr][lq * 8 + 4] = make_uint2(bv.z, bv.w);
    }
    __syncthreads();
    short8v af[4], bf[4];
#pragma unroll
    for (int mi = 0; mi < 4; ++mi) {
      const unsigned short* ap = &Al[wc + mi * 16 + lm][lk];
      union { uint2 p[2]; short8v v; } u;
      u.p[0] = *(const uint2*)ap;
      u.p[1] = *(const uint2*)(ap + 16);
      af[mi] = u.v;
    }
#pragma unroll
    for (int ni = 0; ni < 4; ++ni) {
      const unsigned short* bp = &Bl[wx + ni * 16 + lm][lk];
      union { uint2 p[2]; short8v v; } u;
      u.p[0] = *(const uint2*)bp;
      u.p[1] = *(const uint2*)(bp + 16);
      bf[ni] = u.v;
    }
#pragma unroll
    for (int mi = 0; mi < 4; ++mi)
#pragma unroll
      for (int ni = 0; ni < 4; ++ni)
        acc[mi][ni] = __builtin_amdgcn_mfma_f32_16x16x32_bf16(af[mi], bf[ni], acc[mi][ni], 0, 0, 0);
    __syncthreads();
  }
  int lr4 = (l >> 4) * 4;
  unsigned short* dst = m ? ohb : ow;
#pragma unroll
  for (int ni = 0; ni < 4; ++ni) {
    int xx = wx + ni * 16 + lm;
    float idv = invd[(size_t)(b * 128 + s) * 128 + xx];
#pragma unroll
    for (int mi = 0; mi < 4; ++mi) {
#pragma unroll
      for (int r = 0; r < 4; ++r) {
        int c = wc + mi * 16 + lr4 + r;
        size_t idx = m ? ((size_t)b * 8388608 + (size_t)s * 16384 + (size_t)c * 128 + xx)
                       : ((((size_t)(b * 128 + c)) * 128 + s) * 128 + xx);
        dst[idx] = f2bf(acc[mi][ni][r] * idv);
      }
    }
  }
}

// K5: final out = g*(ow + oh^T) + x.
__global__ void merge2(const unsigned short* __restrict__ ow,
                       const unsigned short* __restrict__ ohp,
                       const float* __restrict__ xin, const float* __restrict__ gamma,
                       float* __restrict__ outp) {
  __shared__ float tile[64][65];
  int blk = blockIdx.x;
  int q = blk & 3, c = (blk >> 2) & 127, b = blk >> 9;
  int h0 = (q >> 1) * 64, w0 = (q & 1) * 64;
  int t = threadIdx.x, lane = t & 63, r0 = (t >> 6) * 16;
  for (int r = r0; r < r0 + 16; ++r)
    tile[r][lane] =
        bf2f(ohp[(size_t)b * 8388608ULL + (size_t)(w0 + r) * 16384 + c * 128 + h0 + lane]);
  __syncthreads();
  float g = gamma[0];
  for (int r = r0; r < r0 + 16; ++r) {
    size_t a = (((size_t)(b * 128 + c)) * 128 + h0 + r) * 128 + w0 + lane;
    outp[a] = g * (bf2f(ow[a]) + tile[lane][r]) + xin[a];
  }
}

// K6: attn writer.
template <int HM>
__global__ void ret_write(const unsigned short* __restrict__ src, const float* __restrict__ invd,
                          float* __restrict__ retb, size_t sbs, size_t soff) {
  __shared__ float tile[128][129];
  __shared__ float idv[128];
  int slab = blockIdx.x;            // b*128 + i
  int b = slab >> 7, i = slab & 127;
  int t = threadIdx.x;
  const unsigned short* sp = src + (size_t)b * sbs + soff;
#pragma unroll
  for (int r = 0; r < 8; ++r) {
    int idx = r * 2048 + t * 8;
    int j = idx >> 7, y = idx & 127;
    uint4 raw;
    if (HM == 0)
      raw = *(const uint4*)(sp + (size_t)i * 16384 + j * 128 + y);
    else
      raw = *(const uint4*)(sp + (size_t)j * 16384 + i * 128 + y);
    unsigned int wd[4] = {raw.x, raw.y, raw.z, raw.w};
#pragma unroll
    for (int e = 0; e < 4; ++e) {
      tile[j][y + 2 * e]     = __uint_as_float((wd[e] & 0xFFFFu) << 16);
      tile[j][y + 2 * e + 1] = __uint_as_float(wd[e] & 0xFFFF0000u);
    }
  }
  if (t < 128) idv[t] = invd[(size_t)slab * 128 + t];
  __syncthreads();
  float* dp = retb + (size_t)b * BSTR_ + (HM == 0 ? SLOT_ : 0);
#pragma unroll
  for (int r = 0; r < 16; ++r) {
    int idx = r * 1024 + t * 4;
    int y = idx >> 7, j = idx & 127;
    float4 o;
    o.x = tile[j][y]     * idv[j];
    o.y = tile[j + 1][y] * idv[j + 1];
    o.z = tile[j + 2][y] * idv[j + 2];
    o.w = tile[j + 3][y] * idv[j + 3];
    *(float4*)&dp[(size_t)y * 16384 + i * 128 + j] = o;
  }
}

extern "C" void kernel_launch(void* const* d_in, const int* in_sizes, int n_in,
                              void* d_out, int out_size, void* d_ws, size_t ws_size,
                              hipStream_t stream) {
  const float* x     = (const float*)d_in[0];
  const float* Wq    = (const float*)d_in[1];
  const float* bq    = (const float*)d_in[2];
  const float* Wk    = (const float*)d_in[3];
  const float* bk    = (const float*)d_in[4];
  const float* Wv    = (const float*)d_in[5];
  const float* bv    = (const float*)d_in[6];
  const float* gamma = (const float*)d_in[7];

  float* outp = (float*)d_out;                 // final out (8M floats)
  float* retb = outp + (size_t)8388608;        // attn region [b][2][y][i][j]
  unsigned short* ohb = (unsigned short*)retb; // bf16 oh in even slots (pre-ret_write)
  unsigned short* ehb = (unsigned short*)retb; // bf16 E_h in odd slots

  float* ws      = (float*)d_ws;
  float* qT      = ws + (size_t)2097152;
  float* kT      = ws + (size_t)3145728;
  unsigned short* ow  = (unsigned short*)ws;
  unsigned short* vA0 = (unsigned short*)(ws + (size_t)4194304);
  unsigned short* vA1 = (unsigned short*)(ws + (size_t)8388608);
  unsigned short* E_w = (unsigned short*)(ws + (size_t)12582912);
  float* rsum_w  = ws + (size_t)16777216;
  float* rsum_h  = ws + (size_t)16842752;
  float* invd_ij = ws + (size_t)16908288;
  float* invd_ji = ws + (size_t)16973824;

  qkv_proj<<<512, 256, 0, stream>>>(x, Wq, bq, Wk, bk, Wv, bv,
                                    qT, kT, vA0, E_w, rsum_w);
  score_h<<<512, 256, 0, stream>>>(qT, kT, ehb, rsum_h,
                                   (size_t)8388608, (size_t)4194304);
  trans_v<<<2048, 256, 0, stream>>>(vA0, vA1, rsum_w, rsum_h, invd_ij, invd_ji);
  pv2<<<1024, 256, 0, stream>>>(vA0, vA1, E_w, ehb, invd_ij, invd_ji, ow, ohb);
  merge2<<<2048, 256, 0, stream>>>(ow, ohb, x, gamma, outp);
  ret_write<1><<<512, 256, 0, stream>>>(ehb, invd_ij, retb, (size_t)8388608, (size_t)4194304);
  ret_write<0><<<512, 256, 0, stream>>>(E_w, invd_ij, retb, (size_t)2097152, (size_t)0);
}